// Round 1
// baseline (975.432 us; speedup 1.0000x reference)
//
#include <hip/hip_runtime.h>
#include <math.h>

// Problem constants
#define B_  8
#define N_  128
#define T_  64
#define D_  512
#define H_  8
#define HD_ 64

typedef __attribute__((ext_vector_type(4))) float  f32x4;
typedef __attribute__((ext_vector_type(8))) __bf16 bf16x8;

// ---------------------------------------------------------------------------
// K1: z_map = mean over T of h_map  [B*N, D]
// ---------------------------------------------------------------------------
__global__ __launch_bounds__(256) void zmap_kernel(const float* __restrict__ hmap,
                                                   float* __restrict__ z) {
  const int bn = blockIdx.x;                       // 0..1023
  const float* src = hmap + (size_t)bn * (T_ * D_);
  int d = threadIdx.x;
#pragma unroll
  for (int rep = 0; rep < 2; rep++, d += 256) {
    float s = 0.f;
#pragma unroll 8
    for (int t = 0; t < T_; t++) s += src[t * D_ + d];
    z[(size_t)bn * D_ + d] = s * (1.f / T_);
  }
}

// ---------------------------------------------------------------------------
// Generic 64x64-tile bf16 MFMA GEMM computing C = A @ W^T  (K = 512 fixed)
//   MODE 0: A fp32, Out fp32 row-major [M,512]                (q/k proj)
//   MODE 1: A fp32 (h_val), Out bf16 scattered to v[B,H,N,T,HD]
//   MODE 2: A bf16 (mixed), Out fp32 = h_val + acc*scale      (o proj)
// grid: (8 n-tiles, M/64 m-tiles); block 256 (4 waves)
// ---------------------------------------------------------------------------
template<int MODE>
__global__ __launch_bounds__(256) void gemm_bt(const void* __restrict__ A_,
    const float* __restrict__ W, void* __restrict__ Out,
    const float* __restrict__ hval, const float* __restrict__ rscale) {
  __shared__ __bf16 As[64][72];   // pad 72 -> row stride 144B (16B aligned, 2-way bank max)
  __shared__ __bf16 Bs[64][72];
  const int tid  = threadIdx.x;
  const int n0   = blockIdx.x * 64;
  const int m0   = blockIdx.y * 64;
  const int lane = tid & 63, wv = tid >> 6;
  const int quad = lane >> 4, l15 = lane & 15;
  const int sr   = tid >> 2;                       // staging row 0..63

  f32x4 acc[4] = {};

  for (int kc = 0; kc < 512; kc += 64) {
    // ---- stage A tile [64 rows m][64 cols k] ----
    if (MODE == 2) {
      const __bf16* A = (const __bf16*)A_;
#pragma unroll
      for (int i = 0; i < 2; i++) {
        int c = ((tid & 3) << 3) + (i << 5);
        *(bf16x8*)&As[sr][c] = *(const bf16x8*)&A[(size_t)(m0 + sr) * 512 + kc + c];
      }
    } else {
      const float* A = (const float*)A_;
#pragma unroll
      for (int i = 0; i < 4; i++) {
        int c = ((tid & 3) << 2) + (i << 4);
        f32x4 v = *(const f32x4*)&A[(size_t)(m0 + sr) * 512 + kc + c];
        As[sr][c + 0] = (__bf16)v[0]; As[sr][c + 1] = (__bf16)v[1];
        As[sr][c + 2] = (__bf16)v[2]; As[sr][c + 3] = (__bf16)v[3];
      }
    }
    // ---- stage B tile: weight rows d = n0..n0+63 (fp32 -> bf16) ----
#pragma unroll
    for (int i = 0; i < 4; i++) {
      int c = ((tid & 3) << 2) + (i << 4);
      f32x4 v = *(const f32x4*)&W[(size_t)(n0 + sr) * 512 + kc + c];
      Bs[sr][c + 0] = (__bf16)v[0]; Bs[sr][c + 1] = (__bf16)v[1];
      Bs[sr][c + 2] = (__bf16)v[2]; Bs[sr][c + 3] = (__bf16)v[3];
    }
    __syncthreads();
    // ---- compute: wave wv owns rows [wv*16, wv*16+16) x 64 cols ----
#pragma unroll
    for (int ks = 0; ks < 64; ks += 32) {
      bf16x8 a = *(const bf16x8*)&As[(wv << 4) + l15][ks + (quad << 3)];
#pragma unroll
      for (int ct = 0; ct < 4; ct++) {
        bf16x8 b = *(const bf16x8*)&Bs[(ct << 4) + l15][ks + (quad << 3)];
        acc[ct] = __builtin_amdgcn_mfma_f32_16x16x32_bf16(a, b, acc[ct], 0, 0, 0);
      }
    }
    __syncthreads();
  }

  // ---- epilogue: D layout col = lane&15, row = quad*4 + reg ----
#pragma unroll
  for (int ct = 0; ct < 4; ct++) {
#pragma unroll
    for (int r = 0; r < 4; r++) {
      const size_t m = (size_t)m0 + (wv << 4) + (quad << 2) + r;
      const size_t n = (size_t)n0 + (ct << 4) + l15;
      float val = acc[ct][r];
      if (MODE == 0) {
        ((float*)Out)[m * 512 + n] = val;
      } else if (MODE == 1) {
        // m = ((b*128 + j)*64 + t), n = h*64 + e -> v[b][h][j][t][e]
        size_t b = m >> 13, j = (m >> 6) & 127, tt = m & 63;
        size_t h = n >> 6, e = n & 63;
        ((__bf16*)Out)[(((b * 8 + h) * 128 + j) * 64 + tt) * 64 + e] = (__bf16)val;
      } else {
        int i = (int)((m >> 6) & 127);
        float sc = fminf(fmaxf(rscale[i], 0.f), 1.f);
        ((float*)Out)[m * 512 + n] = hval[m * 512 + n] + val * sc;
      }
    }
  }
}

// ---------------------------------------------------------------------------
// K3: per-(b,h) scores + bias + raw softmax + top-16 softmax.
// block = 256 threads (4 waves); each wave handles rows i = wv, wv+4, ...
// lane holds j and j+64. Writes attn (bf16, full 128 row with zeros) to ws,
// atomicAdds head-means (/8) into pre-zeroed d_out regions.
// ---------------------------------------------------------------------------
__global__ __launch_bounds__(256) void scores_kernel(
    const float* __restrict__ qb, const float* __restrict__ kb,
    const float* __restrict__ adj, __bf16* __restrict__ attnw,
    float* __restrict__ attn_mean, float* __restrict__ raw_mean) {
  __shared__ float  qs[128][64];   // broadcast reads -> no conflict
  __shared__ __bf16 ks_[128][66];  // stride 33 dwords -> 2-way max (free)
  const int bh = blockIdx.x, b = bh >> 3, h = bh & 7;
  const int tid = threadIdx.x;
  {
    int i = tid >> 1, eb = (tid & 1) << 5;
    const float* qsrc = qb + ((size_t)(b * 128 + i)) * 512 + h * 64 + eb;
    const float* ksrc = kb + ((size_t)(b * 128 + i)) * 512 + h * 64 + eb;
#pragma unroll
    for (int v = 0; v < 8; v++) {
      f32x4 qv = *(const f32x4*)&qsrc[v * 4];
      f32x4 kv = *(const f32x4*)&ksrc[v * 4];
      *(f32x4*)&qs[i][eb + v * 4] = qv;
      ks_[i][eb + v * 4 + 0] = (__bf16)kv[0];
      ks_[i][eb + v * 4 + 1] = (__bf16)kv[1];
      ks_[i][eb + v * 4 + 2] = (__bf16)kv[2];
      ks_[i][eb + v * 4 + 3] = (__bf16)kv[3];
    }
  }
  __syncthreads();
  const int wv = tid >> 6, lane = tid & 63;
  for (int i = wv; i < 128; i += 4) {
    const int j0 = lane, j1 = lane + 64;
    float s0 = 0.f, s1 = 0.f;
#pragma unroll 16
    for (int e = 0; e < 64; e++) {
      float qe = qs[i][e];
      s0 += qe * (float)ks_[j0][e];
      s1 += qe * (float)ks_[j1][e];
    }
    const size_t arow = ((size_t)b * 128 + i) * 128;
    s0 = s0 * 0.125f + logf(fmaxf(adj[arow + j0], 1e-12f));
    s1 = s1 * 0.125f + logf(fmaxf(adj[arow + j1], 1e-12f));
    // raw softmax over 128
    float mx = fmaxf(s0, s1);
#pragma unroll
    for (int off = 32; off; off >>= 1) mx = fmaxf(mx, __shfl_xor(mx, off));
    float e0 = expf(s0 - mx), e1 = expf(s1 - mx);
    float sum = e0 + e1;
#pragma unroll
    for (int off = 32; off; off >>= 1) sum += __shfl_xor(sum, off);
    float inv = 0.125f / sum;
    atomicAdd(&raw_mean[arow + j0], e0 * inv);
    atomicAdd(&raw_mean[arow + j1], e1 * inv);
    // top-16 (ties -> lowest index, matching jax.lax.top_k)
    float w0 = s0, w1 = s1;
    bool sel0 = false, sel1 = false;
    float m16 = 0.f, denom = 0.f;
    for (int it = 0; it < 16; it++) {
      float v; int idx;
      if (w1 > w0) { v = w1; idx = j1; } else { v = w0; idx = j0; }
#pragma unroll
      for (int off = 32; off; off >>= 1) {
        float ov = __shfl_xor(v, off);
        int   oi = __shfl_xor(idx, off);
        if (ov > v || (ov == v && oi < idx)) { v = ov; idx = oi; }
      }
      if (it == 0) m16 = v;
      denom += expf(v - m16);
      if (idx == j0) { sel0 = true; w0 = -INFINITY; }
      if (idx == j1) { sel1 = true; w1 = -INFINITY; }
    }
    const float invd = 1.f / denom;
    const float p0 = sel0 ? expf(s0 - m16) * invd : 0.f;
    const float p1 = sel1 ? expf(s1 - m16) * invd : 0.f;
    const size_t ab = ((size_t)bh * 128 + i) * 128;
    attnw[ab + j0] = (__bf16)p0;
    attnw[ab + j1] = (__bf16)p1;
    if (sel0) atomicAdd(&attn_mean[arow + j0], p0 * 0.125f);
    if (sel1) atomicAdd(&attn_mean[arow + j1], p1 * 0.125f);
  }
}

// ---------------------------------------------------------------------------
// K4: mixed = attn @ V as dense MFMA GEMM per (b,h): [128 i x 128 j] @ [128 j x 4096 te]
// block handles one 64-wide n-tile; V tile transposed into LDS for B-fragments.
// Output scattered to mixed[B,N,T,D] bf16 (o-proj A layout).
// grid: (64 n-tiles, 64 bh)
// ---------------------------------------------------------------------------
__global__ __launch_bounds__(256) void mix_kernel(
    const __bf16* __restrict__ attnw, const __bf16* __restrict__ vbuf,
    __bf16* __restrict__ mixed) {
  __shared__ __bf16 As[128][136];  // attn rows (k = j contiguous)
  __shared__ __bf16 Bt[64][136];   // V^T: [n][j]
  const int nt = blockIdx.x;       // 0..63
  const int bh = blockIdx.y;       // 0..63
  const int b = bh >> 3, h = bh & 7;
  const int n0 = nt << 6;
  const int tid = threadIdx.x;
  {  // stage attn [128][128]
    int i = tid >> 1, cb = (tid & 1) << 6;
    const __bf16* src = attnw + ((size_t)bh * 128 + i) * 128 + cb;
#pragma unroll
    for (int v = 0; v < 8; v++)
      *(bf16x8*)&As[i][cb + (v << 3)] = *(const bf16x8*)&src[v << 3];
  }
  {  // stage V^T [64 n][128 j] (coalesced read along n, scatter-write transpose)
    int j = tid >> 1, cb = (tid & 1) << 5;
    const __bf16* src = vbuf + ((size_t)bh * 128 + j) * 4096 + n0 + cb;
#pragma unroll
    for (int v = 0; v < 4; v++) {
      bf16x8 x = *(const bf16x8*)&src[v << 3];
#pragma unroll
      for (int u = 0; u < 8; u++) Bt[cb + (v << 3) + u][j] = x[u];
    }
  }
  __syncthreads();
  const int lane = tid & 63, wv = tid >> 6;
  const int quad = lane >> 4, l15 = lane & 15;
  f32x4 acc[2][4] = {};
#pragma unroll
  for (int kk = 0; kk < 128; kk += 32) {
    bf16x8 a0 = *(const bf16x8*)&As[(wv << 5) + l15][kk + (quad << 3)];
    bf16x8 a1 = *(const bf16x8*)&As[(wv << 5) + 16 + l15][kk + (quad << 3)];
#pragma unroll
    for (int ct = 0; ct < 4; ct++) {
      bf16x8 bb = *(const bf16x8*)&Bt[(ct << 4) + l15][kk + (quad << 3)];
      acc[0][ct] = __builtin_amdgcn_mfma_f32_16x16x32_bf16(a0, bb, acc[0][ct], 0, 0, 0);
      acc[1][ct] = __builtin_amdgcn_mfma_f32_16x16x32_bf16(a1, bb, acc[1][ct], 0, 0, 0);
    }
  }
  const int tt = nt;  // n0>>6
#pragma unroll
  for (int rt = 0; rt < 2; rt++)
#pragma unroll
    for (int ct = 0; ct < 4; ct++)
#pragma unroll
      for (int r = 0; r < 4; r++) {
        int i = (wv << 5) + (rt << 4) + (quad << 2) + r;
        int e = (ct << 4) + l15;
        mixed[(((size_t)b * 128 + i) * 64 + tt) * 512 + h * 64 + e] =
            (__bf16)acc[rt][ct][r];
      }
}

// ---------------------------------------------------------------------------
extern "C" void kernel_launch(void* const* d_in, const int* in_sizes, int n_in,
                              void* d_out, int out_size, void* d_ws, size_t ws_size,
                              hipStream_t stream) {
  (void)in_sizes; (void)n_in; (void)out_size; (void)ws_size;
  const float* h_val = (const float*)d_in[0];
  const float* h_map = (const float*)d_in[1];
  const float* adj   = (const float*)d_in[2];
  const float* q_w   = (const float*)d_in[3];
  const float* k_w   = (const float*)d_in[4];
  const float* v_w   = (const float*)d_in[5];
  const float* o_w   = (const float*)d_in[6];
  const float* rsc   = (const float*)d_in[7];

  char* ws = (char*)d_ws;
  float*  zmap  = (float*)(ws);                                  // 2 MiB
  float*  qb    = (float*)(ws + (2ull << 20));                   // 2 MiB
  float*  kb    = (float*)(ws + (4ull << 20));                   // 2 MiB
  __bf16* attnw = (__bf16*)(ws + (6ull << 20));                  // 2 MiB
  __bf16* vbuf  = (__bf16*)(ws + (8ull << 20));                  // 64 MiB
  __bf16* mixed = (__bf16*)(ws + (8ull << 20) + (64ull << 20));  // 64 MiB

  float* out       = (float*)d_out;
  float* attn_mean = out + 33554432ull;     // B*N*T*D
  float* raw_mean  = attn_mean + 131072ull; // B*N*N

  zmap_kernel<<<1024, 256, 0, stream>>>(h_map, zmap);
  gemm_bt<0><<<dim3(8, 16), 256, 0, stream>>>(zmap, q_w, qb, nullptr, nullptr);
  gemm_bt<0><<<dim3(8, 16), 256, 0, stream>>>(zmap, k_w, kb, nullptr, nullptr);
  hipMemsetAsync(attn_mean, 0, 2ull * 131072ull * sizeof(float), stream);
  scores_kernel<<<64, 256, 0, stream>>>(qb, kb, adj, attnw, attn_mean, raw_mean);
  gemm_bt<1><<<dim3(8, 1024), 256, 0, stream>>>(h_val, v_w, vbuf, nullptr, nullptr);
  mix_kernel<<<dim3(64, 64), 256, 0, stream>>>(attnw, vbuf, mixed);
  gemm_bt<2><<<dim3(8, 1024), 256, 0, stream>>>(mixed, o_w, d_out, h_val, rsc);
}

// Round 2
// 545.275 us; speedup vs baseline: 1.7889x; 1.7889x over previous
//
#include <hip/hip_runtime.h>
#include <math.h>

#define B_  8
#define N_  128
#define T_  64
#define D_  512
#define H_  8
#define HD_ 64

typedef __attribute__((ext_vector_type(4))) float  f32x4;
typedef __attribute__((ext_vector_type(8))) __bf16 bf16x8;

__device__ __forceinline__ void async_copy16(const void* g, void* l) {
  __builtin_amdgcn_global_load_lds(
      (const __attribute__((address_space(1))) unsigned int*)g,
      (__attribute__((address_space(3))) unsigned int*)l, 16, 0, 0);
}

// ---------------------------------------------------------------------------
// K1: z_map = mean over T of h_map  [B*N, D]
// ---------------------------------------------------------------------------
__global__ __launch_bounds__(256) void zmap_kernel(const float* __restrict__ hmap,
                                                   float* __restrict__ z) {
  const int bn = blockIdx.x;
  const float* src = hmap + (size_t)bn * (T_ * D_);
  int d = threadIdx.x;
#pragma unroll
  for (int rep = 0; rep < 2; rep++, d += 256) {
    float s = 0.f;
#pragma unroll 8
    for (int t = 0; t < T_; t++) s += src[t * D_ + d];
    z[(size_t)bn * D_ + d] = s * (1.f / T_);
  }
}

// ---------------------------------------------------------------------------
// fp32 -> bf16 pre-convert (n multiple of 2048; grid = n/2048)
// ---------------------------------------------------------------------------
__global__ __launch_bounds__(256) void cvt_kernel(const float* __restrict__ s,
                                                  __bf16* __restrict__ d) {
  size_t i = ((size_t)blockIdx.x * 256 + threadIdx.x) << 3;
  f32x4 a = *(const f32x4*)&s[i];
  f32x4 b = *(const f32x4*)&s[i + 4];
  bf16x8 o;
  o[0] = (__bf16)a[0]; o[1] = (__bf16)a[1]; o[2] = (__bf16)a[2]; o[3] = (__bf16)a[3];
  o[4] = (__bf16)b[0]; o[5] = (__bf16)b[1]; o[6] = (__bf16)b[2]; o[7] = (__bf16)b[3];
  *(bf16x8*)&d[i] = o;
}

// ---------------------------------------------------------------------------
// K2: small q/k projection GEMM (M=1024), fp32 A/W, 64x64 tile (round-1 code)
// ---------------------------------------------------------------------------
__global__ __launch_bounds__(256) void qk_gemm(const float* __restrict__ A,
    const float* __restrict__ W, float* __restrict__ Out) {
  __shared__ __bf16 As[64][72];
  __shared__ __bf16 Bs[64][72];
  const int tid  = threadIdx.x;
  const int n0   = blockIdx.x * 64;
  const int m0   = blockIdx.y * 64;
  const int lane = tid & 63, wv = tid >> 6;
  const int quad = lane >> 4, l15 = lane & 15;
  const int sr   = tid >> 2;
  f32x4 acc[4] = {};
  for (int kc = 0; kc < 512; kc += 64) {
#pragma unroll
    for (int i = 0; i < 4; i++) {
      int c = ((tid & 3) << 2) + (i << 4);
      f32x4 v = *(const f32x4*)&A[(size_t)(m0 + sr) * 512 + kc + c];
      As[sr][c + 0] = (__bf16)v[0]; As[sr][c + 1] = (__bf16)v[1];
      As[sr][c + 2] = (__bf16)v[2]; As[sr][c + 3] = (__bf16)v[3];
      f32x4 w = *(const f32x4*)&W[(size_t)(n0 + sr) * 512 + kc + c];
      Bs[sr][c + 0] = (__bf16)w[0]; Bs[sr][c + 1] = (__bf16)w[1];
      Bs[sr][c + 2] = (__bf16)w[2]; Bs[sr][c + 3] = (__bf16)w[3];
    }
    __syncthreads();
#pragma unroll
    for (int ks = 0; ks < 64; ks += 32) {
      bf16x8 a = *(const bf16x8*)&As[(wv << 4) + l15][ks + (quad << 3)];
#pragma unroll
      for (int ct = 0; ct < 4; ct++) {
        bf16x8 b = *(const bf16x8*)&Bs[(ct << 4) + l15][ks + (quad << 3)];
        acc[ct] = __builtin_amdgcn_mfma_f32_16x16x32_bf16(a, b, acc[ct], 0, 0, 0);
      }
    }
    __syncthreads();
  }
#pragma unroll
  for (int ct = 0; ct < 4; ct++)
#pragma unroll
    for (int r = 0; r < 4; r++) {
      const size_t m = (size_t)m0 + (wv << 4) + (quad << 2) + r;
      const size_t n = (size_t)n0 + (ct << 4) + l15;
      Out[m * 512 + n] = acc[ct][r];
    }
}

// ---------------------------------------------------------------------------
// Big GEMM: C = A @ W^T, A bf16 [M,512], W bf16 [512,512], 128x128 tile, BK=64
// global_load_lds (16B) staging for A and B, XOR-swizzled 16B granules.
//   MODE 1: Out bf16 scattered to v[B,H,N,T,HD]
//   MODE 2: Out fp32 = h_val + acc*clamp(scale)
// grid: (4 n-tiles, 512 m-tiles), block 256 (4 waves, each 64x64 output)
// ---------------------------------------------------------------------------
template<int MODE>
__global__ __launch_bounds__(256) void gemm128(const __bf16* __restrict__ A,
    const __bf16* __restrict__ Wb, void* __restrict__ Out,
    const float* __restrict__ hval, const float* __restrict__ rscale) {
  __align__(16) __shared__ __bf16 As[128 * 64];
  __align__(16) __shared__ __bf16 Bs[128 * 64];
  const int tid = threadIdx.x;
  const int lane = tid & 63, wv = tid >> 6;
  const int n0 = blockIdx.x << 7;
  const int m0 = blockIdx.y << 7;
  const int quad = lane >> 4, l15 = lane & 15;
  const int mq = (wv >> 1) << 6, nq = (wv & 1) << 6;
  f32x4 acc[4][4] = {};

  for (int kc = 0; kc < 512; kc += 64) {
    // stage: granule s holds row m = s>>3, chunk c = (s&7) ^ (m&7)  (16B each)
#pragma unroll
    for (int it = 0; it < 4; it++) {
      const int gb = (wv << 8) + (it << 6);      // wave-uniform granule base
      const int s  = gb + lane;
      const int m  = s >> 3, c = (s & 7) ^ (m & 7);
      async_copy16(A  + (size_t)(m0 + m) * 512 + kc + (c << 3), &As[gb << 3]);
      async_copy16(Wb + (size_t)(n0 + m) * 512 + kc + (c << 3), &Bs[gb << 3]);
    }
    __syncthreads();
#pragma unroll
    for (int k0 = 0; k0 < 64; k0 += 32) {
      const int cc = (k0 >> 3) + quad;           // chunk index 0..7
      bf16x8 af[4], bfr[4];
#pragma unroll
      for (int mt = 0; mt < 4; mt++) {
        int m = mq + (mt << 4) + l15;
        af[mt] = *(const bf16x8*)&As[((m << 3) + (cc ^ (m & 7))) << 3];
      }
#pragma unroll
      for (int nt = 0; nt < 4; nt++) {
        int n = nq + (nt << 4) + l15;
        bfr[nt] = *(const bf16x8*)&Bs[((n << 3) + (cc ^ (n & 7))) << 3];
      }
#pragma unroll
      for (int mt = 0; mt < 4; mt++)
#pragma unroll
        for (int nt = 0; nt < 4; nt++)
          acc[mt][nt] = __builtin_amdgcn_mfma_f32_16x16x32_bf16(af[mt], bfr[nt],
                                                                acc[mt][nt], 0, 0, 0);
    }
    __syncthreads();
  }

#pragma unroll
  for (int mt = 0; mt < 4; mt++)
#pragma unroll
    for (int nt = 0; nt < 4; nt++)
#pragma unroll
      for (int r = 0; r < 4; r++) {
        const size_t m = (size_t)m0 + mq + (mt << 4) + (quad << 2) + r;
        const size_t n = (size_t)n0 + nq + (nt << 4) + l15;
        float val = acc[mt][nt][r];
        if (MODE == 1) {
          size_t b = m >> 13, j = (m >> 6) & 127, tt = m & 63;
          size_t h = n >> 6, e = n & 63;
          ((__bf16*)Out)[(((b * 8 + h) * 128 + j) * 64 + tt) * 64 + e] = (__bf16)val;
        } else {
          int i = (int)((m >> 6) & 127);
          float sc = fminf(fmaxf(rscale[i], 0.f), 1.f);
          ((float*)Out)[m * 512 + n] = hval[m * 512 + n] + val * sc;
        }
      }
}

// ---------------------------------------------------------------------------
// K3: scores + bias + raw softmax + top-16 softmax. One wave per row i.
// grid: (32 i-groups, 64 bh); block 256 (4 waves).
// ---------------------------------------------------------------------------
__global__ __launch_bounds__(256) void scores_kernel(
    const float* __restrict__ qb, const float* __restrict__ kb,
    const float* __restrict__ adj, __bf16* __restrict__ attnw,
    float* __restrict__ attn_mean, float* __restrict__ raw_mean) {
  __shared__ float  qs[4][64];
  __shared__ __bf16 ks_[128][66];
  const int ig = blockIdx.x, bh = blockIdx.y;
  const int b = bh >> 3, h = bh & 7;
  const int tid = threadIdx.x;
  {
    int r = tid >> 1, cb = (tid & 1) << 5;
    const float* ksrc = kb + ((size_t)(b * 128 + r)) * 512 + h * 64 + cb;
#pragma unroll
    for (int v = 0; v < 8; v++) {
      f32x4 kv = *(const f32x4*)&ksrc[v * 4];
      ks_[r][cb + v * 4 + 0] = (__bf16)kv[0];
      ks_[r][cb + v * 4 + 1] = (__bf16)kv[1];
      ks_[r][cb + v * 4 + 2] = (__bf16)kv[2];
      ks_[r][cb + v * 4 + 3] = (__bf16)kv[3];
    }
  }
  {
    int r = tid >> 6, ln = tid & 63;
    qs[r][ln] = qb[((size_t)(b * 128 + (ig << 2) + r)) * 512 + h * 64 + ln];
  }
  __syncthreads();
  const int wv = tid >> 6, lane = tid & 63;
  const int i = (ig << 2) + wv;
  const int j0 = lane, j1 = lane + 64;
  float s0 = 0.f, s1 = 0.f;
#pragma unroll 16
  for (int e = 0; e < 64; e++) {
    float qe = qs[wv][e];
    s0 += qe * (float)ks_[j0][e];
    s1 += qe * (float)ks_[j1][e];
  }
  const size_t arow = ((size_t)b * 128 + i) * 128;
  s0 = s0 * 0.125f + logf(fmaxf(adj[arow + j0], 1e-12f));
  s1 = s1 * 0.125f + logf(fmaxf(adj[arow + j1], 1e-12f));
  // raw softmax over 128
  float mx = fmaxf(s0, s1);
#pragma unroll
  for (int off = 32; off; off >>= 1) mx = fmaxf(mx, __shfl_xor(mx, off));
  float e0 = expf(s0 - mx), e1 = expf(s1 - mx);
  float sum = e0 + e1;
#pragma unroll
  for (int off = 32; off; off >>= 1) sum += __shfl_xor(sum, off);
  float inv = 0.125f / sum;
  atomicAdd(&raw_mean[arow + j0], e0 * inv);
  atomicAdd(&raw_mean[arow + j1], e1 * inv);
  // top-16 (ties -> lowest index, matching jax.lax.top_k)
  float w0 = s0, w1 = s1;
  bool sel0 = false, sel1 = false;
  float m16 = 0.f, denom = 0.f;
  for (int it = 0; it < 16; it++) {
    float v; int idx;
    if (w1 > w0) { v = w1; idx = j1; } else { v = w0; idx = j0; }
#pragma unroll
    for (int off = 32; off; off >>= 1) {
      float ov = __shfl_xor(v, off);
      int   oi = __shfl_xor(idx, off);
      if (ov > v || (ov == v && oi < idx)) { v = ov; idx = oi; }
    }
    if (it == 0) m16 = v;
    denom += expf(v - m16);
    if (idx == j0) { sel0 = true; w0 = -INFINITY; }
    if (idx == j1) { sel1 = true; w1 = -INFINITY; }
  }
  const float invd = 1.f / denom;
  const float p0 = sel0 ? expf(s0 - m16) * invd : 0.f;
  const float p1 = sel1 ? expf(s1 - m16) * invd : 0.f;
  const size_t ab = ((size_t)bh * 128 + i) * 128;
  attnw[ab + j0] = (__bf16)p0;
  attnw[ab + j1] = (__bf16)p1;
  if (sel0) atomicAdd(&attn_mean[arow + j0], p0 * 0.125f);
  if (sel1) atomicAdd(&attn_mean[arow + j1], p1 * 0.125f);
}

// ---------------------------------------------------------------------------
// K4: mixed = attn @ V dense MFMA per (b,h). grid (64 n-tiles, 64 bh).
// ---------------------------------------------------------------------------
__global__ __launch_bounds__(256) void mix_kernel(
    const __bf16* __restrict__ attnw, const __bf16* __restrict__ vbuf,
    __bf16* __restrict__ mixed) {
  __shared__ __bf16 As[128][136];
  __shared__ __bf16 Bt[64][136];
  const int nt = blockIdx.x;
  const int bh = blockIdx.y;
  const int b = bh >> 3, h = bh & 7;
  const int n0 = nt << 6;
  const int tid = threadIdx.x;
  {
    int i = tid >> 1, cb = (tid & 1) << 6;
    const __bf16* src = attnw + ((size_t)bh * 128 + i) * 128 + cb;
#pragma unroll
    for (int v = 0; v < 8; v++)
      *(bf16x8*)&As[i][cb + (v << 3)] = *(const bf16x8*)&src[v << 3];
  }
  {
    int j = tid >> 1, cb = (tid & 1) << 5;
    const __bf16* src = vbuf + ((size_t)bh * 128 + j) * 4096 + n0 + cb;
#pragma unroll
    for (int v = 0; v < 4; v++) {
      bf16x8 x = *(const bf16x8*)&src[v << 3];
#pragma unroll
      for (int u = 0; u < 8; u++) Bt[cb + (v << 3) + u][j] = x[u];
    }
  }
  __syncthreads();
  const int lane = tid & 63, wv = tid >> 6;
  const int quad = lane >> 4, l15 = lane & 15;
  f32x4 acc[2][4] = {};
#pragma unroll
  for (int kk = 0; kk < 128; kk += 32) {
    bf16x8 a0 = *(const bf16x8*)&As[(wv << 5) + l15][kk + (quad << 3)];
    bf16x8 a1 = *(const bf16x8*)&As[(wv << 5) + 16 + l15][kk + (quad << 3)];
#pragma unroll
    for (int ct = 0; ct < 4; ct++) {
      bf16x8 bb = *(const bf16x8*)&Bt[(ct << 4) + l15][kk + (quad << 3)];
      acc[0][ct] = __builtin_amdgcn_mfma_f32_16x16x32_bf16(a0, bb, acc[0][ct], 0, 0, 0);
      acc[1][ct] = __builtin_amdgcn_mfma_f32_16x16x32_bf16(a1, bb, acc[1][ct], 0, 0, 0);
    }
  }
  const int tt = nt;
#pragma unroll
  for (int rt = 0; rt < 2; rt++)
#pragma unroll
    for (int ct = 0; ct < 4; ct++)
#pragma unroll
      for (int r = 0; r < 4; r++) {
        int i = (wv << 5) + (rt << 4) + (quad << 2) + r;
        int e = (ct << 4) + l15;
        mixed[(((size_t)b * 128 + i) * 64 + tt) * 512 + h * 64 + e] =
            (__bf16)acc[rt][ct][r];
      }
}

// ---------------------------------------------------------------------------
extern "C" void kernel_launch(void* const* d_in, const int* in_sizes, int n_in,
                              void* d_out, int out_size, void* d_ws, size_t ws_size,
                              hipStream_t stream) {
  (void)in_sizes; (void)n_in; (void)out_size; (void)ws_size;
  const float* h_val = (const float*)d_in[0];
  const float* h_map = (const float*)d_in[1];
  const float* adj   = (const float*)d_in[2];
  const float* q_w   = (const float*)d_in[3];
  const float* k_w   = (const float*)d_in[4];
  const float* v_w   = (const float*)d_in[5];
  const float* o_w   = (const float*)d_in[6];
  const float* rsc   = (const float*)d_in[7];

  char* ws = (char*)d_ws;
  float*  zmap  = (float*)(ws);                         // 2 MiB (dead after qk gemms)
  __bf16* vwb   = (__bf16*)(ws);                        // 512 KiB (aliases zmap)
  __bf16* owb   = (__bf16*)(ws + (512ull << 10));       // 512 KiB
  float*  qb    = (float*)(ws + (2ull << 20));          // 2 MiB
  float*  kb    = (float*)(ws + (4ull << 20));          // 2 MiB
  __bf16* attnw = (__bf16*)(ws + (6ull << 20));         // 2 MiB
  __bf16* hvalb = (__bf16*)(ws + (8ull << 20));         // 64 MiB (dead after v-proj)
  __bf16* mixed = (__bf16*)(ws + (8ull << 20));         // 64 MiB (aliases hvalb)
  __bf16* vbuf  = (__bf16*)(ws + (72ull << 20));        // 64 MiB

  float* out       = (float*)d_out;
  float* attn_mean = out + 33554432ull;
  float* raw_mean  = attn_mean + 131072ull;

  zmap_kernel<<<1024, 256, 0, stream>>>(h_map, zmap);
  qk_gemm<<<dim3(8, 16), 256, 0, stream>>>(zmap, q_w, qb);
  qk_gemm<<<dim3(8, 16), 256, 0, stream>>>(zmap, k_w, kb);
  cvt_kernel<<<128, 256, 0, stream>>>(v_w, vwb);        // zmap now dead
  cvt_kernel<<<128, 256, 0, stream>>>(o_w, owb);
  cvt_kernel<<<16384, 256, 0, stream>>>(h_val, hvalb);
  hipMemsetAsync(attn_mean, 0, 2ull * 131072ull * sizeof(float), stream);
  scores_kernel<<<dim3(32, 64), 256, 0, stream>>>(qb, kb, adj, attnw, attn_mean, raw_mean);
  gemm128<1><<<dim3(4, 512), 256, 0, stream>>>(hvalb, vwb, vbuf, nullptr, nullptr);
  mix_kernel<<<dim3(64, 64), 256, 0, stream>>>(attnw, vbuf, mixed);
  gemm128<2><<<dim3(4, 512), 256, 0, stream>>>(mixed, owb, d_out, h_val, rsc);
}